// Round 1
// 203.014 us; speedup vs baseline: 1.0358x; 1.0358x over previous
//
#include <hip/hip_runtime.h>
#include <math.h>

#define N_NODES 25000
#define N_EDGES 400000
#define EMBED   128
#define HEADS   8
#define DK      16
#define MAXDEG  96        // Poisson(16) max over 25000 nodes ~ 40; 96 is ultra-safe
#define NX (N_NODES * 128)

typedef __attribute__((ext_vector_type(8))) short bf16x8;
typedef __attribute__((ext_vector_type(4))) float f32x4;
typedef unsigned int uint;
typedef unsigned short ushort;

__device__ inline uint pack2_bf16(float a, float b) {
    union { float f; uint u; } ua, ub;
    ua.f = a; ub.f = b;
    uint ra = (ua.u + 0x7FFFu + ((ua.u >> 16) & 1u)) >> 16;
    uint rb = (ub.u + 0x7FFFu + ((ub.u >> 16) & 1u)) >> 16;
    return (ra & 0xFFFFu) | (rb << 16);
}
__device__ inline ushort cvt_bf16(float a) {
    union { float f; uint u; } ua; ua.f = a;
    return (ushort)((ua.u + 0x7FFFu + ((ua.u >> 16) & 1u)) >> 16);
}
__device__ inline float bf16_lo(uint u) {
    union { uint u; float f; } x; x.u = u << 16; return x.f;
}
__device__ inline float bf16_hi(uint u) {
    union { uint u; float f; } x; x.u = u & 0xFFFF0000u; return x.f;
}

// ---------------------------------------------------------------------------
// prep: convert the four 128x128 weights to bf16 (2 floats/thread) and zero
// the degree counters. 128 blocks x 256 = 32768 threads >= max(32768 pairs,
// 25000 nodes).
// ---------------------------------------------------------------------------
__global__ __launch_bounds__(256) void prep(
    const float* __restrict__ Wq, const float* __restrict__ Wk,
    const float* __restrict__ Wv, const float* __restrict__ Wo,
    ushort* __restrict__ wb, int* __restrict__ deg)
{
    int i = blockIdx.x * 256 + threadIdx.x;
    if (i < N_NODES) deg[i] = 0;
    if (i < 32768) {
        int j = i * 2;
        const float* src = (j < 16384) ? Wq + j
                         : (j < 32768) ? Wk + (j - 16384)
                         : (j < 49152) ? Wv + (j - 32768)
                         :               Wo + (j - 49152);
        float2 v = *reinterpret_cast<const float2*>(src);
        reinterpret_cast<uint*>(wb)[i] = pack2_bf16(v.x, v.y);
    }
}

// ---------------------------------------------------------------------------
// Single-pass padded-CSR build: pos = atomicAdd(deg[dst]) appends {e, src}
// into dst's fixed-size slot array. Replaces histogram + 3-level scan +
// scatter (4 dependent launches) with one.
// ---------------------------------------------------------------------------
__global__ __launch_bounds__(256) void scatter_edges(
    const int* __restrict__ ei, int* __restrict__ deg,
    int2* __restrict__ csr2)
{
    int e = blockIdx.x * 256 + threadIdx.x;
    if (e >= N_EDGES) return;
    int dst = ei[e];
    int src = ei[N_EDGES + e];
    int pos = atomicAdd(&deg[dst], 1);
    if (pos < MAXDEG) csr2[dst * MAXDEG + pos] = make_int2(e, src);
}

// ---------------------------------------------------------------------------
// Fused Q/K/V GEMM. Reads fp32 x directly (no xb intermediate), converts the
// A-fragments to bf16 in-register ONCE, then runs all three weight matrices
// against the same fragments. Row-major bf16 outputs.
// ---------------------------------------------------------------------------
__global__ __launch_bounds__(256) void gemm_qkv(
    const float* __restrict__ x, const ushort* __restrict__ Wall,
    const float* __restrict__ bq, const float* __restrict__ bk,
    const float* __restrict__ bv,
    ushort* __restrict__ Qb, ushort* __restrict__ Kb, ushort* __restrict__ Vb)
{
    const int lane = threadIdx.x & 63;
    const int wave = threadIdx.x >> 6;
    const int ml   = lane & 15;
    const int quad = lane >> 4;
    const int m0   = blockIdx.x * 64 + wave * 16;

    int arow = m0 + ml; if (arow >= N_NODES) arow = N_NODES - 1;
    const float* xp = x + arow * 128 + quad * 8;

    // A fragments for all 4 K-steps, converted once
    bf16x8 af[4];
#pragma unroll
    for (int ks = 0; ks < 4; ++ks) {
        float4 a0 = *reinterpret_cast<const float4*>(xp + ks * 32);
        float4 a1 = *reinterpret_cast<const float4*>(xp + ks * 32 + 4);
        uint* u = reinterpret_cast<uint*>(&af[ks]);
        u[0] = pack2_bf16(a0.x, a0.y); u[1] = pack2_bf16(a0.z, a0.w);
        u[2] = pack2_bf16(a1.x, a1.y); u[3] = pack2_bf16(a1.z, a1.w);
    }

#pragma unroll
    for (int which = 0; which < 3; ++which) {
        const ushort* W = Wall + which * 16384;
        f32x4 acc[8];
#pragma unroll
        for (int ct = 0; ct < 8; ++ct) acc[ct] = (f32x4){0.f, 0.f, 0.f, 0.f};

#pragma unroll
        for (int ks = 0; ks < 4; ++ks) {
#pragma unroll
            for (int ct = 0; ct < 8; ++ct) {
                bf16x8 bf = *reinterpret_cast<const bf16x8*>(
                    W + (ct * 16 + ml) * 128 + ks * 32 + quad * 8);
                acc[ct] = __builtin_amdgcn_mfma_f32_16x16x32_bf16(af[ks], bf, acc[ct], 0, 0, 0);
            }
        }

        const float* bias = (which == 0) ? bq : (which == 1) ? bk : bv;
        ushort* C = (which == 0) ? Qb : (which == 1) ? Kb : Vb;
#pragma unroll
        for (int ct = 0; ct < 8; ++ct) {
            int col = ct * 16 + ml;
            float b = bias[col];
#pragma unroll
            for (int r = 0; r < 4; ++r) {
                int row = m0 + quad * 4 + r;
                if (row < N_NODES)
                    C[row * 128 + col] = cvt_bf16(acc[ct][r] + b);
            }
        }
    }
}

// Final projection: AGG bf16 [M,128] @ Wo^T + bias -> fp32 out
__global__ __launch_bounds__(256) void gemm_out(
    const ushort* __restrict__ A, const ushort* __restrict__ W,
    const float* __restrict__ bias, float* __restrict__ C, int M)
{
    const int lane = threadIdx.x & 63;
    const int wave = threadIdx.x >> 6;
    const int ml   = lane & 15;
    const int quad = lane >> 4;
    const int m0   = blockIdx.x * 64 + wave * 16;

    int arow = m0 + ml; if (arow >= M) arow = M - 1;
    const ushort* ap = A + arow * 128 + quad * 8;

    f32x4 acc[8];
#pragma unroll
    for (int ct = 0; ct < 8; ++ct) acc[ct] = (f32x4){0.f, 0.f, 0.f, 0.f};

#pragma unroll
    for (int ks = 0; ks < 128; ks += 32) {
        bf16x8 af = *reinterpret_cast<const bf16x8*>(ap + ks);
#pragma unroll
        for (int ct = 0; ct < 8; ++ct) {
            bf16x8 bf = *reinterpret_cast<const bf16x8*>(
                W + (ct * 16 + ml) * 128 + ks + quad * 8);
            acc[ct] = __builtin_amdgcn_mfma_f32_16x16x32_bf16(af, bf, acc[ct], 0, 0, 0);
        }
    }

#pragma unroll
    for (int ct = 0; ct < 8; ++ct) {
        int col = ct * 16 + ml;
        float bv_ = bias[col];
#pragma unroll
        for (int r = 0; r < 4; ++r) {
            int row = m0 + quad * 4 + r;
            if (row < M)
                C[row * 128 + col] = acc[ct][r] + bv_;
        }
    }
}

// ---------------------------------------------------------------------------
// Fused attention: one wave per node, one (edge, head) per lane
// (e_slot = lane>>3, h = lane&7). Full 16-dim dot serially per lane,
// exp once per (e,h), accumulate p*V into 16 regs. Reduce-scatter butterfly
// over the 3 e_slot bits at the end. Padded CSR; next-batch csr2 pair
// prefetched to break the csr2 -> gather dependence chain.
// ---------------------------------------------------------------------------
__global__ __launch_bounds__(256) void fused_attn(
    const ushort* __restrict__ Q2, const ushort* __restrict__ K2,
    const ushort* __restrict__ V2,
    const float* __restrict__ attn_bias,
    const int* __restrict__ deg, const int2* __restrict__ csr2,
    float* __restrict__ logits, ushort* __restrict__ AGG)
{
    const int lane = threadIdx.x & 63;
    const int wid  = threadIdx.x >> 6;
    const int n = blockIdx.x * 4 + wid;
    int dg = deg[n]; if (dg > MAXDEG) dg = MAXDEG;
    const int start = n * MAXDEG;
    const int h  = lane & 7;
    const int es = lane >> 3;

    const uint4* Qu4 = reinterpret_cast<const uint4*>(Q2);
    const uint4* Ku4 = reinterpret_cast<const uint4*>(K2);
    const uint4* Vu4 = reinterpret_cast<const uint4*>(V2);

    // Q[n, h*16 .. +16) -> 16 floats (broadcast across the 8 e_slots)
    uint4 qa = Qu4[n * 16 + h * 2];
    uint4 qb = Qu4[n * 16 + h * 2 + 1];
    float qf[16];
    {
        uint qq[8] = {qa.x, qa.y, qa.z, qa.w, qb.x, qb.y, qb.z, qb.w};
#pragma unroll
        for (int j = 0; j < 8; ++j) {
            qf[2 * j]     = bf16_lo(qq[j]);
            qf[2 * j + 1] = bf16_hi(qq[j]);
        }
    }

    float acc[16];
#pragma unroll
    for (int j = 0; j < 16; ++j) acc[j] = 0.f;
    float z = 0.f;

    if (dg > 0) {
        int2 ep = csr2[start + (es < dg ? es : dg - 1)];
        for (int base = 0; base < dg; base += 8) {
            int e = ep.x, s = ep.y;
            bool valid = (base + es) < dg;

            uint4 k0 = Ku4[s * 16 + h * 2];
            uint4 k1 = Ku4[s * 16 + h * 2 + 1];
            uint4 v0 = Vu4[s * 16 + h * 2];
            uint4 v1 = Vu4[s * 16 + h * 2 + 1];
            float bias = attn_bias[e * 8 + h];

            // prefetch next batch's {e, src} before the VALU work
            int nb = base + 8;
            if (nb < dg) {
                int t2 = nb + es; if (t2 >= dg) t2 = dg - 1;
                ep = csr2[start + t2];
            }

            uint kk[8] = {k0.x, k0.y, k0.z, k0.w, k1.x, k1.y, k1.z, k1.w};
            float d = 0.f;
#pragma unroll
            for (int j = 0; j < 8; ++j)
                d += qf[2 * j] * bf16_lo(kk[j]) + qf[2 * j + 1] * bf16_hi(kk[j]);

            float l = 0.25f * d + bias;
            float p = 0.f;
            if (valid) {
                __builtin_nontemporal_store(l, &logits[e * 8 + h]);
                p = __expf(l);
            }
            z += p;

            uint vv[8] = {v0.x, v0.y, v0.z, v0.w, v1.x, v1.y, v1.z, v1.w};
#pragma unroll
            for (int j = 0; j < 8; ++j) {
                acc[2 * j]     += p * bf16_lo(vv[j]);
                acc[2 * j + 1] += p * bf16_hi(vv[j]);
            }
        }
    }

    // reduce-scatter butterfly over e_slot bits (lane bits 5,4,3)
    {
        int bit = (lane >> 5) & 1;
#pragma unroll
        for (int j = 0; j < 8; ++j) {
            float send = bit ? acc[j] : acc[j + 8];
            float keep = bit ? acc[j + 8] : acc[j];
            acc[j] = keep + __shfl_xor(send, 32, 64);
        }
        bit = (lane >> 4) & 1;
#pragma unroll
        for (int j = 0; j < 4; ++j) {
            float send = bit ? acc[j] : acc[j + 4];
            float keep = bit ? acc[j + 4] : acc[j];
            acc[j] = keep + __shfl_xor(send, 16, 64);
        }
        bit = (lane >> 3) & 1;
#pragma unroll
        for (int j = 0; j < 2; ++j) {
            float send = bit ? acc[j] : acc[j + 2];
            float keep = bit ? acc[j + 2] : acc[j];
            acc[j] = keep + __shfl_xor(send, 8, 64);
        }
    }
    z += __shfl_xor(z, 8, 64);
    z += __shfl_xor(z, 16, 64);
    z += __shfl_xor(z, 32, 64);

    float inv = (z > 0.f) ? 1.f / z : 0.f;
    int d_off = ((lane >> 5) & 1) * 8 + ((lane >> 4) & 1) * 4 + ((lane >> 3) & 1) * 2;
    reinterpret_cast<uint*>(AGG)[n * 64 + h * 8 + (d_off >> 1)] =
        pack2_bf16(acc[0] * inv, acc[1] * inv);
}

// ---------------------------------------------------------------------------
extern "C" void kernel_launch(void* const* d_in, const int* in_sizes, int n_in,
                              void* d_out, int out_size, void* d_ws, size_t ws_size,
                              hipStream_t stream)
{
    const float* x         = (const float*)d_in[0];
    const int*   ei        = (const int*)  d_in[1];
    const float* attn_bias = (const float*)d_in[2];
    const float* Wq = (const float*)d_in[3];
    const float* bq = (const float*)d_in[4];
    const float* Wk = (const float*)d_in[5];
    const float* bk = (const float*)d_in[6];
    const float* Wv = (const float*)d_in[7];
    const float* bv = (const float*)d_in[8];
    const float* Wo = (const float*)d_in[9];
    const float* bo = (const float*)d_in[10];

    float* out    = (float*)d_out;                // [N,128]
    float* logits = out + N_NODES * EMBED;        // [E,8] (output 1)

    ushort* wb   = (ushort*)d_ws;                 // 4*16384 (Wq,Wk,Wv,Wo)
    ushort* Qb   = wb + 4 * 16384;                // N*128
    ushort* Kb   = Qb + NX;                       // N*128
    ushort* Vb   = Kb + NX;                       // N*128
    ushort* AGGb = Vb + NX;                       // N*128
    int* deg     = (int*)(AGGb + NX);             // N (doubles as append cursor)
    int2* csr2   = (int2*)(deg + N_NODES);        // N*MAXDEG pairs {edge, src}

    prep<<<128, 256, 0, stream>>>(Wq, Wk, Wv, Wo, wb, deg);

    scatter_edges<<<(N_EDGES + 255) / 256, 256, 0, stream>>>(ei, deg, csr2);

    int gblocks = (N_NODES + 63) / 64;            // 391
    gemm_qkv<<<gblocks, 256, 0, stream>>>(x, wb, bq, bk, bv, Qb, Kb, Vb);

    fused_attn<<<N_NODES / 4, 256, 0, stream>>>(Qb, Kb, Vb, attn_bias,
                                                deg, csr2, logits, AGGb);

    gemm_out<<<gblocks, 256, 0, stream>>>(AGGb, wb + 3 * 16384, bo, out, N_NODES);
}

// Round 2
// 198.489 us; speedup vs baseline: 1.0594x; 1.0228x over previous
//
#include <hip/hip_runtime.h>
#include <math.h>

#define N_NODES 25000
#define N_EDGES 400000
#define EMBED   128
#define HEADS   8
#define DK      16
#define MAXDEG  96        // Poisson(16) max over 25000 nodes ~ 40; 96 is ultra-safe
#define NX (N_NODES * 128)
#define SCAT_BLOCKS ((N_EDGES + 255) / 256)   // 1563

typedef __attribute__((ext_vector_type(8))) short bf16x8;
typedef __attribute__((ext_vector_type(4))) float f32x4;
typedef unsigned int uint;
typedef unsigned short ushort;

__device__ inline uint pack2_bf16(float a, float b) {
    union { float f; uint u; } ua, ub;
    ua.f = a; ub.f = b;
    uint ra = (ua.u + 0x7FFFu + ((ua.u >> 16) & 1u)) >> 16;
    uint rb = (ub.u + 0x7FFFu + ((ub.u >> 16) & 1u)) >> 16;
    return (ra & 0xFFFFu) | (rb << 16);
}
__device__ inline ushort cvt_bf16(float a) {
    union { float f; uint u; } ua; ua.f = a;
    return (ushort)((ua.u + 0x7FFFu + ((ua.u >> 16) & 1u)) >> 16);
}
__device__ inline float bf16_lo(uint u) {
    union { uint u; float f; } x; x.u = u << 16; return x.f;
}
__device__ inline float bf16_hi(uint u) {
    union { uint u; float f; } x; x.u = u & 0xFFFF0000u; return x.f;
}

// ---------------------------------------------------------------------------
// Merged prep + scatter. Blocks [0,128): convert 4 weight matrices to bf16.
// Blocks [128, 128+1563): padded-CSR atomic-append scatter. deg is zeroed by
// a hipMemsetAsync before this kernel (stream-ordered).
// ---------------------------------------------------------------------------
__global__ __launch_bounds__(256) void prep_scatter(
    const float* __restrict__ Wq, const float* __restrict__ Wk,
    const float* __restrict__ Wv, const float* __restrict__ Wo,
    ushort* __restrict__ wb,
    const int* __restrict__ ei, int* __restrict__ deg,
    int2* __restrict__ csr2)
{
    if (blockIdx.x < 128) {
        int i = blockIdx.x * 256 + threadIdx.x;   // pair index, 32768 total
        int j = i * 2;
        const float* src = (j < 16384) ? Wq + j
                         : (j < 32768) ? Wk + (j - 16384)
                         : (j < 49152) ? Wv + (j - 32768)
                         :               Wo + (j - 49152);
        float2 v = *reinterpret_cast<const float2*>(src);
        reinterpret_cast<uint*>(wb)[i] = pack2_bf16(v.x, v.y);
    } else {
        int e = (blockIdx.x - 128) * 256 + threadIdx.x;
        if (e >= N_EDGES) return;
        int dst = ei[e];
        int src = ei[N_EDGES + e];
        int pos = atomicAdd(&deg[dst], 1);
        if (pos < MAXDEG) csr2[dst * MAXDEG + pos] = make_int2(e, src);
    }
}

// ---------------------------------------------------------------------------
// Q/K/V GEMM, one weight matrix per blockIdx.y (3x the waves of the fused
// version -> 4.6 waves/SIMD to hide the global B-load latency). Reads fp32 x
// directly, converts A-fragments in-register. Row-major bf16 outputs.
// ---------------------------------------------------------------------------
__global__ __launch_bounds__(256) void gemm_qkv(
    const float* __restrict__ x, const ushort* __restrict__ Wall,
    const float* __restrict__ bq, const float* __restrict__ bk,
    const float* __restrict__ bv,
    ushort* __restrict__ Qb, ushort* __restrict__ Kb, ushort* __restrict__ Vb)
{
    const int which = blockIdx.y;
    const ushort* W = Wall + which * 16384;
    const float* bias = (which == 0) ? bq : (which == 1) ? bk : bv;
    ushort* C = (which == 0) ? Qb : (which == 1) ? Kb : Vb;

    const int lane = threadIdx.x & 63;
    const int wave = threadIdx.x >> 6;
    const int ml   = lane & 15;
    const int quad = lane >> 4;
    const int m0   = blockIdx.x * 64 + wave * 16;

    int arow = m0 + ml; if (arow >= N_NODES) arow = N_NODES - 1;
    const float* xp = x + arow * 128 + quad * 8;

    // A fragments for all 4 K-steps, converted once
    bf16x8 af[4];
#pragma unroll
    for (int ks = 0; ks < 4; ++ks) {
        float4 a0 = *reinterpret_cast<const float4*>(xp + ks * 32);
        float4 a1 = *reinterpret_cast<const float4*>(xp + ks * 32 + 4);
        uint* u = reinterpret_cast<uint*>(&af[ks]);
        u[0] = pack2_bf16(a0.x, a0.y); u[1] = pack2_bf16(a0.z, a0.w);
        u[2] = pack2_bf16(a1.x, a1.y); u[3] = pack2_bf16(a1.z, a1.w);
    }

    f32x4 acc[8];
#pragma unroll
    for (int ct = 0; ct < 8; ++ct) acc[ct] = (f32x4){0.f, 0.f, 0.f, 0.f};

#pragma unroll
    for (int ks = 0; ks < 4; ++ks) {
#pragma unroll
        for (int ct = 0; ct < 8; ++ct) {
            bf16x8 bf = *reinterpret_cast<const bf16x8*>(
                W + (ct * 16 + ml) * 128 + ks * 32 + quad * 8);
            acc[ct] = __builtin_amdgcn_mfma_f32_16x16x32_bf16(af[ks], bf, acc[ct], 0, 0, 0);
        }
    }

#pragma unroll
    for (int ct = 0; ct < 8; ++ct) {
        int col = ct * 16 + ml;
        float b = bias[col];
#pragma unroll
        for (int r = 0; r < 4; ++r) {
            int row = m0 + quad * 4 + r;
            if (row < N_NODES)
                C[row * 128 + col] = cvt_bf16(acc[ct][r] + b);
        }
    }
}

// Final projection: AGG bf16 [M,128] @ Wo^T + bias -> fp32 out.
// Column-split across blockIdx.y (64 cols each) for 2x the waves.
__global__ __launch_bounds__(256) void gemm_out(
    const ushort* __restrict__ A, const ushort* __restrict__ W,
    const float* __restrict__ bias, float* __restrict__ C, int M)
{
    const int lane = threadIdx.x & 63;
    const int wave = threadIdx.x >> 6;
    const int ml   = lane & 15;
    const int quad = lane >> 4;
    const int m0   = blockIdx.x * 64 + wave * 16;
    const int ct0  = blockIdx.y * 4;

    int arow = m0 + ml; if (arow >= M) arow = M - 1;
    const ushort* ap = A + arow * 128 + quad * 8;

    f32x4 acc[4];
#pragma unroll
    for (int ct = 0; ct < 4; ++ct) acc[ct] = (f32x4){0.f, 0.f, 0.f, 0.f};

#pragma unroll
    for (int ks = 0; ks < 128; ks += 32) {
        bf16x8 af = *reinterpret_cast<const bf16x8*>(ap + ks);
#pragma unroll
        for (int ct = 0; ct < 4; ++ct) {
            bf16x8 bf = *reinterpret_cast<const bf16x8*>(
                W + ((ct0 + ct) * 16 + ml) * 128 + ks + quad * 8);
            acc[ct] = __builtin_amdgcn_mfma_f32_16x16x32_bf16(af, bf, acc[ct], 0, 0, 0);
        }
    }

#pragma unroll
    for (int ct = 0; ct < 4; ++ct) {
        int col = (ct0 + ct) * 16 + ml;
        float bv_ = bias[col];
#pragma unroll
        for (int r = 0; r < 4; ++r) {
            int row = m0 + quad * 4 + r;
            if (row < M)
                C[row * 128 + col] = acc[ct][r] + bv_;
        }
    }
}

// ---------------------------------------------------------------------------
// Fused attention: one wave per node, one (edge, head) per lane
// (e_slot = lane>>3, h = lane&7). Full 16-dim dot serially per lane,
// exp once per (e,h), accumulate p*V into 16 regs. Reduce-scatter butterfly
// over the 3 e_slot bits at the end. Padded CSR; next-batch csr2 pair
// prefetched to break the csr2 -> gather dependence chain.
// ---------------------------------------------------------------------------
__global__ __launch_bounds__(256) void fused_attn(
    const ushort* __restrict__ Q2, const ushort* __restrict__ K2,
    const ushort* __restrict__ V2,
    const float* __restrict__ attn_bias,
    const int* __restrict__ deg, const int2* __restrict__ csr2,
    float* __restrict__ logits, ushort* __restrict__ AGG)
{
    const int lane = threadIdx.x & 63;
    const int wid  = threadIdx.x >> 6;
    const int n = blockIdx.x * 4 + wid;
    int dg = deg[n]; if (dg > MAXDEG) dg = MAXDEG;
    const int start = n * MAXDEG;
    const int h  = lane & 7;
    const int es = lane >> 3;

    const uint4* Qu4 = reinterpret_cast<const uint4*>(Q2);
    const uint4* Ku4 = reinterpret_cast<const uint4*>(K2);
    const uint4* Vu4 = reinterpret_cast<const uint4*>(V2);

    // Q[n, h*16 .. +16) -> 16 floats (broadcast across the 8 e_slots)
    uint4 qa = Qu4[n * 16 + h * 2];
    uint4 qb = Qu4[n * 16 + h * 2 + 1];
    float qf[16];
    {
        uint qq[8] = {qa.x, qa.y, qa.z, qa.w, qb.x, qb.y, qb.z, qb.w};
#pragma unroll
        for (int j = 0; j < 8; ++j) {
            qf[2 * j]     = bf16_lo(qq[j]);
            qf[2 * j + 1] = bf16_hi(qq[j]);
        }
    }

    float acc[16];
#pragma unroll
    for (int j = 0; j < 16; ++j) acc[j] = 0.f;
    float z = 0.f;

    if (dg > 0) {
        int2 ep = csr2[start + (es < dg ? es : dg - 1)];
        for (int base = 0; base < dg; base += 8) {
            int e = ep.x, s = ep.y;
            bool valid = (base + es) < dg;

            uint4 k0 = Ku4[s * 16 + h * 2];
            uint4 k1 = Ku4[s * 16 + h * 2 + 1];
            uint4 v0 = Vu4[s * 16 + h * 2];
            uint4 v1 = Vu4[s * 16 + h * 2 + 1];
            float bias = attn_bias[e * 8 + h];

            // prefetch next batch's {e, src} before the VALU work
            int nb = base + 8;
            if (nb < dg) {
                int t2 = nb + es; if (t2 >= dg) t2 = dg - 1;
                ep = csr2[start + t2];
            }

            uint kk[8] = {k0.x, k0.y, k0.z, k0.w, k1.x, k1.y, k1.z, k1.w};
            float d = 0.f;
#pragma unroll
            for (int j = 0; j < 8; ++j)
                d += qf[2 * j] * bf16_lo(kk[j]) + qf[2 * j + 1] * bf16_hi(kk[j]);

            float l = 0.25f * d + bias;
            float p = 0.f;
            if (valid) {
                __builtin_nontemporal_store(l, &logits[e * 8 + h]);
                p = __expf(l);
            }
            z += p;

            uint vv[8] = {v0.x, v0.y, v0.z, v0.w, v1.x, v1.y, v1.z, v1.w};
#pragma unroll
            for (int j = 0; j < 8; ++j) {
                acc[2 * j]     += p * bf16_lo(vv[j]);
                acc[2 * j + 1] += p * bf16_hi(vv[j]);
            }
        }
    }

    // reduce-scatter butterfly over e_slot bits (lane bits 5,4,3)
    {
        int bit = (lane >> 5) & 1;
#pragma unroll
        for (int j = 0; j < 8; ++j) {
            float send = bit ? acc[j] : acc[j + 8];
            float keep = bit ? acc[j + 8] : acc[j];
            acc[j] = keep + __shfl_xor(send, 32, 64);
        }
        bit = (lane >> 4) & 1;
#pragma unroll
        for (int j = 0; j < 4; ++j) {
            float send = bit ? acc[j] : acc[j + 4];
            float keep = bit ? acc[j + 4] : acc[j];
            acc[j] = keep + __shfl_xor(send, 16, 64);
        }
        bit = (lane >> 3) & 1;
#pragma unroll
        for (int j = 0; j < 2; ++j) {
            float send = bit ? acc[j] : acc[j + 2];
            float keep = bit ? acc[j + 2] : acc[j];
            acc[j] = keep + __shfl_xor(send, 8, 64);
        }
    }
    z += __shfl_xor(z, 8, 64);
    z += __shfl_xor(z, 16, 64);
    z += __shfl_xor(z, 32, 64);

    float inv = (z > 0.f) ? 1.f / z : 0.f;
    int d_off = ((lane >> 5) & 1) * 8 + ((lane >> 4) & 1) * 4 + ((lane >> 3) & 1) * 2;
    reinterpret_cast<uint*>(AGG)[n * 64 + h * 8 + (d_off >> 1)] =
        pack2_bf16(acc[0] * inv, acc[1] * inv);
}

// ---------------------------------------------------------------------------
extern "C" void kernel_launch(void* const* d_in, const int* in_sizes, int n_in,
                              void* d_out, int out_size, void* d_ws, size_t ws_size,
                              hipStream_t stream)
{
    const float* x         = (const float*)d_in[0];
    const int*   ei        = (const int*)  d_in[1];
    const float* attn_bias = (const float*)d_in[2];
    const float* Wq = (const float*)d_in[3];
    const float* bq = (const float*)d_in[4];
    const float* Wk = (const float*)d_in[5];
    const float* bk = (const float*)d_in[6];
    const float* Wv = (const float*)d_in[7];
    const float* bv = (const float*)d_in[8];
    const float* Wo = (const float*)d_in[9];
    const float* bo = (const float*)d_in[10];

    float* out    = (float*)d_out;                // [N,128]
    float* logits = out + N_NODES * EMBED;        // [E,8] (output 1)

    ushort* wb   = (ushort*)d_ws;                 // 4*16384 (Wq,Wk,Wv,Wo)
    ushort* Qb   = wb + 4 * 16384;                // N*128
    ushort* Kb   = Qb + NX;                       // N*128
    ushort* Vb   = Kb + NX;                       // N*128
    ushort* AGGb = Vb + NX;                       // N*128
    int* deg     = (int*)(AGGb + NX);             // N (doubles as append cursor)
    int2* csr2   = (int2*)(deg + N_NODES);        // N*MAXDEG pairs {edge, src}

    hipMemsetAsync(deg, 0, N_NODES * sizeof(int), stream);

    prep_scatter<<<128 + SCAT_BLOCKS, 256, 0, stream>>>(Wq, Wk, Wv, Wo, wb,
                                                        ei, deg, csr2);

    int gblocks = (N_NODES + 63) / 64;            // 391
    gemm_qkv<<<dim3(gblocks, 3), 256, 0, stream>>>(x, wb, bq, bk, bv, Qb, Kb, Vb);

    fused_attn<<<N_NODES / 4, 256, 0, stream>>>(Qb, Kb, Vb, attn_bias,
                                                deg, csr2, logits, AGGb);

    gemm_out<<<dim3(gblocks, 2), 256, 0, stream>>>(AGGb, wb + 3 * 16384, bo,
                                                   out, N_NODES);
}

// Round 3
// 188.586 us; speedup vs baseline: 1.1151x; 1.0525x over previous
//
#include <hip/hip_runtime.h>
#include <math.h>

#define N_NODES 25000
#define N_EDGES 400000
#define EMBED   128
#define HEADS   8
#define DK      16
#define MAXDEG  96        // Poisson(16) max over 25000 nodes ~ 40; 96 is ultra-safe
#define NX (N_NODES * 128)
#define GBLK 391                         // ceil(25000/64) GEMM row-blocks
#define SCAT_BLK 391                     // ceil(400000/(256*4)) scatter blocks

typedef __attribute__((ext_vector_type(8))) short bf16x8;
typedef __attribute__((ext_vector_type(4))) float f32x4;
typedef unsigned int uint;
typedef unsigned short ushort;

__device__ inline uint pack2_bf16(float a, float b) {
    union { float f; uint u; } ua, ub;
    ua.f = a; ub.f = b;
    uint ra = (ua.u + 0x7FFFu + ((ua.u >> 16) & 1u)) >> 16;
    uint rb = (ub.u + 0x7FFFu + ((ub.u >> 16) & 1u)) >> 16;
    return (ra & 0xFFFFu) | (rb << 16);
}
__device__ inline ushort cvt_bf16(float a) {
    union { float f; uint u; } ua; ua.f = a;
    return (ushort)((ua.u + 0x7FFFu + ((ua.u >> 16) & 1u)) >> 16);
}
__device__ inline float bf16_lo(uint u) {
    union { uint u; float f; } x; x.u = u << 16; return x.f;
}
__device__ inline float bf16_hi(uint u) {
    union { uint u; float f; } x; x.u = u & 0xFFFF0000u; return x.f;
}

// ---------------------------------------------------------------------------
// prep: convert the four 128x128 weights to bf16 (2 floats/thread) and zero
// the degree counters. 128 blocks x 256 = 32768 threads >= max(32768 pairs,
// 25000 nodes). Replaces the separate hipMemsetAsync dispatch.
// ---------------------------------------------------------------------------
__global__ __launch_bounds__(256) void prep(
    const float* __restrict__ Wq, const float* __restrict__ Wk,
    const float* __restrict__ Wv, const float* __restrict__ Wo,
    ushort* __restrict__ wb, int* __restrict__ deg)
{
    int i = blockIdx.x * 256 + threadIdx.x;
    if (i < N_NODES) deg[i] = 0;
    if (i < 32768) {
        int j = i * 2;
        const float* src = (j < 16384) ? Wq + j
                         : (j < 32768) ? Wk + (j - 16384)
                         : (j < 49152) ? Wv + (j - 32768)
                         :               Wo + (j - 49152);
        float2 v = *reinterpret_cast<const float2*>(src);
        reinterpret_cast<uint*>(wb)[i] = pack2_bf16(v.x, v.y);
    }
}

// ---------------------------------------------------------------------------
// Merged Q/K/V GEMM + padded-CSR scatter (independent work, one launch so the
// latency-bound scatter overlaps the MFMA GEMM instead of running alone).
// Blocks [0, 3*GBLK): GEMM, which = bx/GBLK, row-block = bx%GBLK.
// Blocks [3*GBLK, 3*GBLK+SCAT_BLK): scatter, 4 edges/thread via int4.
// ---------------------------------------------------------------------------
__global__ __launch_bounds__(256) void gemm_qkv_scatter(
    const float* __restrict__ x, const ushort* __restrict__ Wall,
    const float* __restrict__ bq, const float* __restrict__ bk,
    const float* __restrict__ bv,
    ushort* __restrict__ Qb, ushort* __restrict__ Kb, ushort* __restrict__ Vb,
    const int* __restrict__ ei, int* __restrict__ deg, int2* __restrict__ csr2)
{
    const int bx = blockIdx.x;
    if (bx >= 3 * GBLK) {
        // ---- scatter: 4 edges per thread ----
        int t = (bx - 3 * GBLK) * 256 + threadIdx.x;
        int e = t * 4;
        if (e < N_EDGES) {   // N_EDGES % 4 == 0, so full int4 is always valid
            int4 d = *reinterpret_cast<const int4*>(ei + e);
            int4 s = *reinterpret_cast<const int4*>(ei + N_EDGES + e);
            int p0 = atomicAdd(&deg[d.x], 1);
            if (p0 < MAXDEG) csr2[d.x * MAXDEG + p0] = make_int2(e, s.x);
            int p1 = atomicAdd(&deg[d.y], 1);
            if (p1 < MAXDEG) csr2[d.y * MAXDEG + p1] = make_int2(e + 1, s.y);
            int p2 = atomicAdd(&deg[d.z], 1);
            if (p2 < MAXDEG) csr2[d.z * MAXDEG + p2] = make_int2(e + 2, s.z);
            int p3 = atomicAdd(&deg[d.w], 1);
            if (p3 < MAXDEG) csr2[d.w * MAXDEG + p3] = make_int2(e + 3, s.w);
        }
        return;
    }

    // ---- GEMM: one weight matrix per GBLK-group ----
    const int which = bx / GBLK;
    const int mb    = bx - which * GBLK;
    const ushort* W = Wall + which * 16384;
    const float* bias = (which == 0) ? bq : (which == 1) ? bk : bv;
    ushort* C = (which == 0) ? Qb : (which == 1) ? Kb : Vb;

    const int lane = threadIdx.x & 63;
    const int wave = threadIdx.x >> 6;
    const int ml   = lane & 15;
    const int quad = lane >> 4;
    const int m0   = mb * 64 + wave * 16;

    int arow = m0 + ml; if (arow >= N_NODES) arow = N_NODES - 1;
    const float* xp = x + arow * 128 + quad * 8;

    // A fragments for all 4 K-steps, converted once
    bf16x8 af[4];
#pragma unroll
    for (int ks = 0; ks < 4; ++ks) {
        float4 a0 = *reinterpret_cast<const float4*>(xp + ks * 32);
        float4 a1 = *reinterpret_cast<const float4*>(xp + ks * 32 + 4);
        uint* u = reinterpret_cast<uint*>(&af[ks]);
        u[0] = pack2_bf16(a0.x, a0.y); u[1] = pack2_bf16(a0.z, a0.w);
        u[2] = pack2_bf16(a1.x, a1.y); u[3] = pack2_bf16(a1.z, a1.w);
    }

    f32x4 acc[8];
#pragma unroll
    for (int ct = 0; ct < 8; ++ct) acc[ct] = (f32x4){0.f, 0.f, 0.f, 0.f};

#pragma unroll
    for (int ks = 0; ks < 4; ++ks) {
#pragma unroll
        for (int ct = 0; ct < 8; ++ct) {
            bf16x8 bf = *reinterpret_cast<const bf16x8*>(
                W + (ct * 16 + ml) * 128 + ks * 32 + quad * 8);
            acc[ct] = __builtin_amdgcn_mfma_f32_16x16x32_bf16(af[ks], bf, acc[ct], 0, 0, 0);
        }
    }

#pragma unroll
    for (int ct = 0; ct < 8; ++ct) {
        int col = ct * 16 + ml;
        float b = bias[col];
#pragma unroll
        for (int r = 0; r < 4; ++r) {
            int row = m0 + quad * 4 + r;
            if (row < N_NODES)
                C[row * 128 + col] = cvt_bf16(acc[ct][r] + b);
        }
    }
}

// Final projection: AGG bf16 [M,128] @ Wo^T + bias -> fp32 out.
// Column-split across blockIdx.y (64 cols each) for 2x the waves.
__global__ __launch_bounds__(256) void gemm_out(
    const ushort* __restrict__ A, const ushort* __restrict__ W,
    const float* __restrict__ bias, float* __restrict__ C, int M)
{
    const int lane = threadIdx.x & 63;
    const int wave = threadIdx.x >> 6;
    const int ml   = lane & 15;
    const int quad = lane >> 4;
    const int m0   = blockIdx.x * 64 + wave * 16;
    const int ct0  = blockIdx.y * 4;

    int arow = m0 + ml; if (arow >= M) arow = M - 1;
    const ushort* ap = A + arow * 128 + quad * 8;

    f32x4 acc[4];
#pragma unroll
    for (int ct = 0; ct < 4; ++ct) acc[ct] = (f32x4){0.f, 0.f, 0.f, 0.f};

#pragma unroll
    for (int ks = 0; ks < 128; ks += 32) {
        bf16x8 af = *reinterpret_cast<const bf16x8*>(ap + ks);
#pragma unroll
        for (int ct = 0; ct < 4; ++ct) {
            bf16x8 bf = *reinterpret_cast<const bf16x8*>(
                W + ((ct0 + ct) * 16 + ml) * 128 + ks + quad * 8);
            acc[ct] = __builtin_amdgcn_mfma_f32_16x16x32_bf16(af, bf, acc[ct], 0, 0, 0);
        }
    }

#pragma unroll
    for (int ct = 0; ct < 4; ++ct) {
        int col = (ct0 + ct) * 16 + ml;
        float bv_ = bias[col];
#pragma unroll
        for (int r = 0; r < 4; ++r) {
            int row = m0 + quad * 4 + r;
            if (row < M)
                C[row * 128 + col] = acc[ct][r] + bv_;
        }
    }
}

// ---------------------------------------------------------------------------
// Fused attention: one wave per node, one (edge, head) per lane
// (e_slot = lane>>3, h = lane&7). Full 16-dim dot serially per lane,
// exp once per (e,h), accumulate p*V into 16 regs. Reduce-scatter butterfly
// over the 3 e_slot bits at the end. Padded CSR; next-batch csr2 pair
// prefetched to break the csr2 -> gather dependence chain.
// ---------------------------------------------------------------------------
__global__ __launch_bounds__(256) void fused_attn(
    const ushort* __restrict__ Q2, const ushort* __restrict__ K2,
    const ushort* __restrict__ V2,
    const float* __restrict__ attn_bias,
    const int* __restrict__ deg, const int2* __restrict__ csr2,
    float* __restrict__ logits, ushort* __restrict__ AGG)
{
    const int lane = threadIdx.x & 63;
    const int wid  = threadIdx.x >> 6;
    const int n = blockIdx.x * 4 + wid;
    int dg = deg[n]; if (dg > MAXDEG) dg = MAXDEG;
    const int start = n * MAXDEG;
    const int h  = lane & 7;
    const int es = lane >> 3;

    const uint4* Qu4 = reinterpret_cast<const uint4*>(Q2);
    const uint4* Ku4 = reinterpret_cast<const uint4*>(K2);
    const uint4* Vu4 = reinterpret_cast<const uint4*>(V2);

    // Q[n, h*16 .. +16) -> 16 floats (broadcast across the 8 e_slots)
    uint4 qa = Qu4[n * 16 + h * 2];
    uint4 qb = Qu4[n * 16 + h * 2 + 1];
    float qf[16];
    {
        uint qq[8] = {qa.x, qa.y, qa.z, qa.w, qb.x, qb.y, qb.z, qb.w};
#pragma unroll
        for (int j = 0; j < 8; ++j) {
            qf[2 * j]     = bf16_lo(qq[j]);
            qf[2 * j + 1] = bf16_hi(qq[j]);
        }
    }

    float acc[16];
#pragma unroll
    for (int j = 0; j < 16; ++j) acc[j] = 0.f;
    float z = 0.f;

    if (dg > 0) {
        int2 ep = csr2[start + (es < dg ? es : dg - 1)];
        for (int base = 0; base < dg; base += 8) {
            int e = ep.x, s = ep.y;
            bool valid = (base + es) < dg;

            uint4 k0 = Ku4[s * 16 + h * 2];
            uint4 k1 = Ku4[s * 16 + h * 2 + 1];
            uint4 v0 = Vu4[s * 16 + h * 2];
            uint4 v1 = Vu4[s * 16 + h * 2 + 1];
            float bias = attn_bias[e * 8 + h];

            // prefetch next batch's {e, src} before the VALU work
            int nb = base + 8;
            if (nb < dg) {
                int t2 = nb + es; if (t2 >= dg) t2 = dg - 1;
                ep = csr2[start + t2];
            }

            uint kk[8] = {k0.x, k0.y, k0.z, k0.w, k1.x, k1.y, k1.z, k1.w};
            float d = 0.f;
#pragma unroll
            for (int j = 0; j < 8; ++j)
                d += qf[2 * j] * bf16_lo(kk[j]) + qf[2 * j + 1] * bf16_hi(kk[j]);

            float l = 0.25f * d + bias;
            float p = 0.f;
            if (valid) {
                __builtin_nontemporal_store(l, &logits[e * 8 + h]);
                p = __expf(l);
            }
            z += p;

            uint vv[8] = {v0.x, v0.y, v0.z, v0.w, v1.x, v1.y, v1.z, v1.w};
#pragma unroll
            for (int j = 0; j < 8; ++j) {
                acc[2 * j]     += p * bf16_lo(vv[j]);
                acc[2 * j + 1] += p * bf16_hi(vv[j]);
            }
        }
    }

    // reduce-scatter butterfly over e_slot bits (lane bits 5,4,3)
    {
        int bit = (lane >> 5) & 1;
#pragma unroll
        for (int j = 0; j < 8; ++j) {
            float send = bit ? acc[j] : acc[j + 8];
            float keep = bit ? acc[j + 8] : acc[j];
            acc[j] = keep + __shfl_xor(send, 32, 64);
        }
        bit = (lane >> 4) & 1;
#pragma unroll
        for (int j = 0; j < 4; ++j) {
            float send = bit ? acc[j] : acc[j + 4];
            float keep = bit ? acc[j + 4] : acc[j];
            acc[j] = keep + __shfl_xor(send, 16, 64);
        }
        bit = (lane >> 3) & 1;
#pragma unroll
        for (int j = 0; j < 2; ++j) {
            float send = bit ? acc[j] : acc[j + 2];
            float keep = bit ? acc[j + 2] : acc[j];
            acc[j] = keep + __shfl_xor(send, 8, 64);
        }
    }
    z += __shfl_xor(z, 8, 64);
    z += __shfl_xor(z, 16, 64);
    z += __shfl_xor(z, 32, 64);

    float inv = (z > 0.f) ? 1.f / z : 0.f;
    int d_off = ((lane >> 5) & 1) * 8 + ((lane >> 4) & 1) * 4 + ((lane >> 3) & 1) * 2;
    reinterpret_cast<uint*>(AGG)[n * 64 + h * 8 + (d_off >> 1)] =
        pack2_bf16(acc[0] * inv, acc[1] * inv);
}

// ---------------------------------------------------------------------------
extern "C" void kernel_launch(void* const* d_in, const int* in_sizes, int n_in,
                              void* d_out, int out_size, void* d_ws, size_t ws_size,
                              hipStream_t stream)
{
    const float* x         = (const float*)d_in[0];
    const int*   ei        = (const int*)  d_in[1];
    const float* attn_bias = (const float*)d_in[2];
    const float* Wq = (const float*)d_in[3];
    const float* bq = (const float*)d_in[4];
    const float* Wk = (const float*)d_in[5];
    const float* bk = (const float*)d_in[6];
    const float* Wv = (const float*)d_in[7];
    const float* bv = (const float*)d_in[8];
    const float* Wo = (const float*)d_in[9];
    const float* bo = (const float*)d_in[10];

    float* out    = (float*)d_out;                // [N,128]
    float* logits = out + N_NODES * EMBED;        // [E,8] (output 1)

    ushort* wb   = (ushort*)d_ws;                 // 4*16384 (Wq,Wk,Wv,Wo)
    ushort* Qb   = wb + 4 * 16384;                // N*128
    ushort* Kb   = Qb + NX;                       // N*128
    ushort* Vb   = Kb + NX;                       // N*128
    ushort* AGGb = Vb + NX;                       // N*128
    int* deg     = (int*)(AGGb + NX);             // N (doubles as append cursor)
    int2* csr2   = (int2*)(deg + N_NODES);        // N*MAXDEG pairs {edge, src}

    prep<<<128, 256, 0, stream>>>(Wq, Wk, Wv, Wo, wb, deg);

    gemm_qkv_scatter<<<3 * GBLK + SCAT_BLK, 256, 0, stream>>>(
        x, wb, bq, bk, bv, Qb, Kb, Vb, ei, deg, csr2);

    fused_attn<<<N_NODES / 4, 256, 0, stream>>>(Qb, Kb, Vb, attn_bias,
                                                deg, csr2, logits, AGGb);

    gemm_out<<<dim3(GBLK, 2), 256, 0, stream>>>(AGGb, wb + 3 * 16384, bo,
                                                out, N_NODES);
}

// Round 4
// 185.848 us; speedup vs baseline: 1.1315x; 1.0147x over previous
//
#include <hip/hip_runtime.h>
#include <math.h>

#define N_NODES 25000
#define N_EDGES 400000
#define EMBED   128
#define HEADS   8
#define DK      16
#define MAXDEG  96        // Poisson(16) max over 25000 nodes ~ 40; 96 is ultra-safe
#define NX (N_NODES * 128)
#define GBLK 391                         // ceil(25000/64) GEMM row-blocks
#define SCAT_BLK 391                     // ceil(400000/(256*4)) scatter blocks

typedef __attribute__((ext_vector_type(8))) short bf16x8;
typedef __attribute__((ext_vector_type(4))) float f32x4;
typedef unsigned int uint;
typedef unsigned short ushort;

__device__ inline uint pack2_bf16(float a, float b) {
    union { float f; uint u; } ua, ub;
    ua.f = a; ub.f = b;
    uint ra = (ua.u + 0x7FFFu + ((ua.u >> 16) & 1u)) >> 16;
    uint rb = (ub.u + 0x7FFFu + ((ub.u >> 16) & 1u)) >> 16;
    return (ra & 0xFFFFu) | (rb << 16);
}
__device__ inline ushort cvt_bf16(float a) {
    union { float f; uint u; } ua; ua.f = a;
    return (ushort)((ua.u + 0x7FFFu + ((ua.u >> 16) & 1u)) >> 16);
}
__device__ inline float bf16_lo(uint u) {
    union { uint u; float f; } x; x.u = u << 16; return x.f;
}
__device__ inline float bf16_hi(uint u) {
    union { uint u; float f; } x; x.u = u & 0xFFFF0000u; return x.f;
}

// ---------------------------------------------------------------------------
// prep: convert the four 128x128 weights to bf16 (2 floats/thread) and zero
// the degree counters.
// ---------------------------------------------------------------------------
__global__ __launch_bounds__(256) void prep(
    const float* __restrict__ Wq, const float* __restrict__ Wk,
    const float* __restrict__ Wv, const float* __restrict__ Wo,
    ushort* __restrict__ wb, int* __restrict__ deg)
{
    int i = blockIdx.x * 256 + threadIdx.x;
    if (i < N_NODES) deg[i] = 0;
    if (i < 32768) {
        int j = i * 2;
        const float* src = (j < 16384) ? Wq + j
                         : (j < 32768) ? Wk + (j - 16384)
                         : (j < 49152) ? Wv + (j - 32768)
                         :               Wo + (j - 49152);
        float2 v = *reinterpret_cast<const float2*>(src);
        reinterpret_cast<uint*>(wb)[i] = pack2_bf16(v.x, v.y);
    }
}

// ---------------------------------------------------------------------------
// Merged Q/K/V GEMM + padded-CSR scatter (independent work, one launch so the
// latency-bound scatter overlaps the MFMA GEMM instead of running alone).
// ---------------------------------------------------------------------------
__global__ __launch_bounds__(256) void gemm_qkv_scatter(
    const float* __restrict__ x, const ushort* __restrict__ Wall,
    const float* __restrict__ bq, const float* __restrict__ bk,
    const float* __restrict__ bv,
    ushort* __restrict__ Qb, ushort* __restrict__ Kb, ushort* __restrict__ Vb,
    const int* __restrict__ ei, int* __restrict__ deg, int2* __restrict__ csr2)
{
    const int bx = blockIdx.x;
    if (bx >= 3 * GBLK) {
        // ---- scatter: 4 edges per thread ----
        int t = (bx - 3 * GBLK) * 256 + threadIdx.x;
        int e = t * 4;
        if (e < N_EDGES) {   // N_EDGES % 4 == 0, so full int4 is always valid
            int4 d = *reinterpret_cast<const int4*>(ei + e);
            int4 s = *reinterpret_cast<const int4*>(ei + N_EDGES + e);
            int p0 = atomicAdd(&deg[d.x], 1);
            if (p0 < MAXDEG) csr2[d.x * MAXDEG + p0] = make_int2(e, s.x);
            int p1 = atomicAdd(&deg[d.y], 1);
            if (p1 < MAXDEG) csr2[d.y * MAXDEG + p1] = make_int2(e + 1, s.y);
            int p2 = atomicAdd(&deg[d.z], 1);
            if (p2 < MAXDEG) csr2[d.z * MAXDEG + p2] = make_int2(e + 2, s.z);
            int p3 = atomicAdd(&deg[d.w], 1);
            if (p3 < MAXDEG) csr2[d.w * MAXDEG + p3] = make_int2(e + 3, s.w);
        }
        return;
    }

    // ---- GEMM: one weight matrix per GBLK-group ----
    const int which = bx / GBLK;
    const int mb    = bx - which * GBLK;
    const ushort* W = Wall + which * 16384;
    const float* bias = (which == 0) ? bq : (which == 1) ? bk : bv;
    ushort* C = (which == 0) ? Qb : (which == 1) ? Kb : Vb;

    const int lane = threadIdx.x & 63;
    const int wave = threadIdx.x >> 6;
    const int ml   = lane & 15;
    const int quad = lane >> 4;
    const int m0   = mb * 64 + wave * 16;

    int arow = m0 + ml; if (arow >= N_NODES) arow = N_NODES - 1;
    const float* xp = x + arow * 128 + quad * 8;

    // A fragments for all 4 K-steps, converted once
    bf16x8 af[4];
#pragma unroll
    for (int ks = 0; ks < 4; ++ks) {
        float4 a0 = *reinterpret_cast<const float4*>(xp + ks * 32);
        float4 a1 = *reinterpret_cast<const float4*>(xp + ks * 32 + 4);
        uint* u = reinterpret_cast<uint*>(&af[ks]);
        u[0] = pack2_bf16(a0.x, a0.y); u[1] = pack2_bf16(a0.z, a0.w);
        u[2] = pack2_bf16(a1.x, a1.y); u[3] = pack2_bf16(a1.z, a1.w);
    }

    f32x4 acc[8];
#pragma unroll
    for (int ct = 0; ct < 8; ++ct) acc[ct] = (f32x4){0.f, 0.f, 0.f, 0.f};

#pragma unroll
    for (int ks = 0; ks < 4; ++ks) {
#pragma unroll
        for (int ct = 0; ct < 8; ++ct) {
            bf16x8 bf = *reinterpret_cast<const bf16x8*>(
                W + (ct * 16 + ml) * 128 + ks * 32 + quad * 8);
            acc[ct] = __builtin_amdgcn_mfma_f32_16x16x32_bf16(af[ks], bf, acc[ct], 0, 0, 0);
        }
    }

#pragma unroll
    for (int ct = 0; ct < 8; ++ct) {
        int col = ct * 16 + ml;
        float b = bias[col];
#pragma unroll
        for (int r = 0; r < 4; ++r) {
            int row = m0 + quad * 4 + r;
            if (row < N_NODES)
                C[row * 128 + col] = cvt_bf16(acc[ct][r] + b);
        }
    }
}

// ---------------------------------------------------------------------------
// Fused attention + output projection. One wave per node (4 nodes/block),
// one (edge, head) per lane. After the butterfly reduction each lane holds 2
// normalized output dims; these are packed bf16 into a per-block LDS tile
// agg_sh[16][136] (row = wave/node, rows 4..15 zeroed). After one barrier,
// wave 0 runs the 16x16x32 MFMA projection (identical fragment pattern to the
// old gemm_out) against Wo and stores fp32 out rows 0..3 + bias. This
// eliminates the fourth serialized kernel and the AGG global round-trip.
// ---------------------------------------------------------------------------
__global__ __launch_bounds__(256) void fused_attn_out(
    const ushort* __restrict__ Q2, const ushort* __restrict__ K2,
    const ushort* __restrict__ V2,
    const float* __restrict__ attn_bias,
    const int* __restrict__ deg, const int2* __restrict__ csr2,
    const ushort* __restrict__ Wo2, const float* __restrict__ bo,
    float* __restrict__ logits, float* __restrict__ out)
{
    __shared__ ushort agg_sh[16 * 136];   // 16 rows x 136 ushorts (272B stride)

    const int tid  = threadIdx.x;
    const int lane = tid & 63;
    const int wid  = tid >> 6;
    const int n0 = blockIdx.x * 4;
    const int n  = n0 + wid;
    int dg = deg[n]; if (dg > MAXDEG) dg = MAXDEG;
    const int start = n * MAXDEG;
    const int h  = lane & 7;
    const int es = lane >> 3;
    const int ml   = lane & 15;
    const int quad = lane >> 4;

    // zero rows 4..15 of agg_sh (disjoint from rows 0..3 written below)
    if (tid < 204)
        *reinterpret_cast<uint4*>(reinterpret_cast<char*>(agg_sh) + 1088 + tid * 16) =
            make_uint4(0u, 0u, 0u, 0u);

    const uint4* Qu4 = reinterpret_cast<const uint4*>(Q2);
    const uint4* Ku4 = reinterpret_cast<const uint4*>(K2);
    const uint4* Vu4 = reinterpret_cast<const uint4*>(V2);

    // Q[n, h*16 .. +16) -> 16 floats (broadcast across the 8 e_slots)
    uint4 qa = Qu4[n * 16 + h * 2];
    uint4 qb = Qu4[n * 16 + h * 2 + 1];
    float qf[16];
    {
        uint qq[8] = {qa.x, qa.y, qa.z, qa.w, qb.x, qb.y, qb.z, qb.w};
#pragma unroll
        for (int j = 0; j < 8; ++j) {
            qf[2 * j]     = bf16_lo(qq[j]);
            qf[2 * j + 1] = bf16_hi(qq[j]);
        }
    }

    float acc[16];
#pragma unroll
    for (int j = 0; j < 16; ++j) acc[j] = 0.f;
    float z = 0.f;

    if (dg > 0) {
        int2 ep = csr2[start + (es < dg ? es : dg - 1)];
        for (int base = 0; base < dg; base += 8) {
            int e = ep.x, s = ep.y;
            bool valid = (base + es) < dg;

            uint4 k0 = Ku4[s * 16 + h * 2];
            uint4 k1 = Ku4[s * 16 + h * 2 + 1];
            uint4 v0 = Vu4[s * 16 + h * 2];
            uint4 v1 = Vu4[s * 16 + h * 2 + 1];
            float bias = attn_bias[e * 8 + h];

            // prefetch next batch's {e, src} before the VALU work
            int nb = base + 8;
            if (nb < dg) {
                int t2 = nb + es; if (t2 >= dg) t2 = dg - 1;
                ep = csr2[start + t2];
            }

            uint kk[8] = {k0.x, k0.y, k0.z, k0.w, k1.x, k1.y, k1.z, k1.w};
            float d = 0.f;
#pragma unroll
            for (int j = 0; j < 8; ++j)
                d += qf[2 * j] * bf16_lo(kk[j]) + qf[2 * j + 1] * bf16_hi(kk[j]);

            float l = 0.25f * d + bias;
            float p = 0.f;
            if (valid) {
                __builtin_nontemporal_store(l, &logits[e * 8 + h]);
                p = __expf(l);
            }
            z += p;

            uint vv[8] = {v0.x, v0.y, v0.z, v0.w, v1.x, v1.y, v1.z, v1.w};
#pragma unroll
            for (int j = 0; j < 8; ++j) {
                acc[2 * j]     += p * bf16_lo(vv[j]);
                acc[2 * j + 1] += p * bf16_hi(vv[j]);
            }
        }
    }

    // reduce-scatter butterfly over e_slot bits (lane bits 5,4,3)
    {
        int bit = (lane >> 5) & 1;
#pragma unroll
        for (int j = 0; j < 8; ++j) {
            float send = bit ? acc[j] : acc[j + 8];
            float keep = bit ? acc[j + 8] : acc[j];
            acc[j] = keep + __shfl_xor(send, 32, 64);
        }
        bit = (lane >> 4) & 1;
#pragma unroll
        for (int j = 0; j < 4; ++j) {
            float send = bit ? acc[j] : acc[j + 4];
            float keep = bit ? acc[j + 4] : acc[j];
            acc[j] = keep + __shfl_xor(send, 16, 64);
        }
        bit = (lane >> 3) & 1;
#pragma unroll
        for (int j = 0; j < 2; ++j) {
            float send = bit ? acc[j] : acc[j + 2];
            float keep = bit ? acc[j + 2] : acc[j];
            acc[j] = keep + __shfl_xor(send, 8, 64);
        }
    }
    z += __shfl_xor(z, 8, 64);
    z += __shfl_xor(z, 16, 64);
    z += __shfl_xor(z, 32, 64);

    float inv = (z > 0.f) ? 1.f / z : 0.f;
    // lane holds output dims h*16 + d_off + {0,1}; write bf16 pair to LDS
    int d_off = ((lane >> 5) & 1) * 8 + ((lane >> 4) & 1) * 4 + ((lane >> 3) & 1) * 2;
    *reinterpret_cast<uint*>(reinterpret_cast<char*>(agg_sh) + wid * 272 +
                             (h * 16 + d_off) * 2) =
        pack2_bf16(acc[0] * inv, acc[1] * inv);

    __syncthreads();

    // ---- wave 0: output projection for the block's 4 nodes via MFMA ----
    if (wid == 0) {
        bf16x8 af[4];
#pragma unroll
        for (int ks = 0; ks < 4; ++ks)
            af[ks] = *reinterpret_cast<const bf16x8*>(
                reinterpret_cast<char*>(agg_sh) + ml * 272 + ks * 64 + quad * 16);

        f32x4 oacc[8];
#pragma unroll
        for (int ct = 0; ct < 8; ++ct) oacc[ct] = (f32x4){0.f, 0.f, 0.f, 0.f};

#pragma unroll
        for (int ks = 0; ks < 4; ++ks) {
#pragma unroll
            for (int ct = 0; ct < 8; ++ct) {
                bf16x8 bf = *reinterpret_cast<const bf16x8*>(
                    Wo2 + (ct * 16 + ml) * 128 + ks * 32 + quad * 8);
                oacc[ct] = __builtin_amdgcn_mfma_f32_16x16x32_bf16(af[ks], bf, oacc[ct], 0, 0, 0);
            }
        }

        if (quad == 0) {   // rows 0..3 = the block's 4 nodes
#pragma unroll
            for (int ct = 0; ct < 8; ++ct) {
                int col = ct * 16 + ml;
                float b = bo[col];
#pragma unroll
                for (int r = 0; r < 4; ++r)
                    out[(n0 + r) * 128 + col] = oacc[ct][r] + b;
            }
        }
    }
}

// ---------------------------------------------------------------------------
extern "C" void kernel_launch(void* const* d_in, const int* in_sizes, int n_in,
                              void* d_out, int out_size, void* d_ws, size_t ws_size,
                              hipStream_t stream)
{
    const float* x         = (const float*)d_in[0];
    const int*   ei        = (const int*)  d_in[1];
    const float* attn_bias = (const float*)d_in[2];
    const float* Wq = (const float*)d_in[3];
    const float* bq = (const float*)d_in[4];
    const float* Wk = (const float*)d_in[5];
    const float* bk = (const float*)d_in[6];
    const float* Wv = (const float*)d_in[7];
    const float* bv = (const float*)d_in[8];
    const float* Wo = (const float*)d_in[9];
    const float* bo = (const float*)d_in[10];

    float* out    = (float*)d_out;                // [N,128]
    float* logits = out + N_NODES * EMBED;        // [E,8] (output 1)

    ushort* wb   = (ushort*)d_ws;                 // 4*16384 (Wq,Wk,Wv,Wo)
    ushort* Qb   = wb + 4 * 16384;                // N*128
    ushort* Kb   = Qb + NX;                       // N*128
    ushort* Vb   = Kb + NX;                       // N*128
    int* deg     = (int*)(Vb + NX);               // N (doubles as append cursor)
    int2* csr2   = (int2*)(deg + N_NODES);        // N*MAXDEG pairs {edge, src}

    prep<<<128, 256, 0, stream>>>(Wq, Wk, Wv, Wo, wb, deg);

    gemm_qkv_scatter<<<3 * GBLK + SCAT_BLK, 256, 0, stream>>>(
        x, wb, bq, bk, bv, Qb, Kb, Vb, ei, deg, csr2);

    fused_attn_out<<<N_NODES / 4, 256, 0, stream>>>(Qb, Kb, Vb, attn_bias,
                                                    deg, csr2, wb + 3 * 16384,
                                                    bo, logits, out);
}